// Round 1
// baseline (6007.642 us; speedup 1.0000x reference)
//
#include <hip/hip_runtime.h>
#include <stdint.h>

typedef __bf16 bf16x8 __attribute__((ext_vector_type(8)));
typedef float f32x4 __attribute__((ext_vector_type(4)));

__device__ __forceinline__ float bf2f(unsigned short h) {
    union { unsigned int u; float f; } v; v.u = ((unsigned int)h) << 16; return v.f;
}
__device__ __forceinline__ unsigned short f2bf(float f) {  // RNE
    union { float f; unsigned int u; } v; v.f = f;
    unsigned int r = (v.u + 0x7FFFu + ((v.u >> 16) & 1u)) >> 16;
    return (unsigned short)r;
}
__device__ __forceinline__ unsigned short f2bf_trunc(float f) {
    union { float f; unsigned int u; } v; v.f = f;
    return (unsigned short)(v.u >> 16);
}
__device__ __forceinline__ bf16x8 ldfrag(const unsigned short* p) {
    uint4 u = *(const uint4*)p; return __builtin_bit_cast(bf16x8, u);
}
__device__ __forceinline__ float fsigm(float x) { return 1.f / (1.f + __expf(-x)); }
__device__ __forceinline__ float ftanh(float x) { float e = __expf(2.f * x); return 1.f - 2.f / (e + 1.f); }

// ---------------- casts / transposes ----------------
__global__ __launch_bounds__(256) void k_cast(const float* __restrict__ src,
                                              unsigned short* __restrict__ dst, int n4) {
    int i = blockIdx.x * 256 + threadIdx.x;
    if (i >= n4) return;
    float4 v = ((const float4*)src)[i];
    union { unsigned short s[4]; uint2 u; } o;
    o.s[0] = f2bf(v.x); o.s[1] = f2bf(v.y); o.s[2] = f2bf(v.z); o.s[3] = f2bf(v.w);
    ((uint2*)dst)[i] = o.u;
}

// src (R,C) fp32 -> dst (C,R) bf16
__global__ __launch_bounds__(256) void k_transpose_bf16(const float* __restrict__ src,
                                                        unsigned short* __restrict__ dst,
                                                        int R, int C) {
    __shared__ float tile[32][33];
    int tc = threadIdx.x & 31, tr = threadIdx.x >> 5;  // tr 0..7
    int r0 = blockIdx.y * 32, c0 = blockIdx.x * 32;
#pragma unroll
    for (int p = 0; p < 4; p++) tile[tr + p * 8][tc] = src[(size_t)(r0 + tr + p * 8) * C + c0 + tc];
    __syncthreads();
#pragma unroll
    for (int p = 0; p < 4; p++) dst[(size_t)(c0 + tr + p * 8) * R + r0 + tc] = f2bf(tile[tc][tr + p * 8]);
}

// ---------------- GEMM1: Zs partials (z on the fly, fused tanh*W2 reduce) ----------------
// grid (4, 128); tile 128(M) x 256(N); K=4096
__global__ __launch_bounds__(256, 2) void k_gemm1(
    const unsigned short* __restrict__ Dc, const unsigned short* __restrict__ Qc,
    const unsigned short* __restrict__ Pc, const unsigned short* __restrict__ W1t,
    const float* __restrict__ b1, const float* __restrict__ W2, float* __restrict__ Zpart) {
    __shared__ alignas(16) unsigned short As[128][40];
    __shared__ alignas(16) unsigned short Bs[256][40];
    __shared__ float red[128];
    const int tid = threadIdx.x;
    const int nt = blockIdx.x, mt = blockIdx.y;
    const int r0 = mt * 128, n0 = nt * 256, b = r0 >> 8;
    const int lane = tid & 63, wid = tid >> 6;
    const int qm = wid & 1, qn = wid >> 1;
    const int nlane = lane & 15, quad = lane >> 4, k0 = quad * 8;

    f32x4 acc[4][8];
#pragma unroll
    for (int im = 0; im < 4; im++)
#pragma unroll
        for (int in = 0; in < 8; in++) acc[im][in] = (f32x4){0.f, 0.f, 0.f, 0.f};

    for (int kt = 0; kt < 128; ++kt) {
        const int q = kt >> 5;               // quarter of z
        const int kq = (kt & 31) * 32;       // k within quarter
        const unsigned short* wsrc = (q & 1) ? Pc : Qc;
        // A: build z tile (128 x 32)
#pragma unroll
        for (int rep = 0; rep < 2; ++rep) {
            int c = tid + rep * 256;
            int row = c >> 2, part = c & 3;
            uint4 d8 = *(const uint4*)(Dc + (size_t)(r0 + row) * 1024 + kq + part * 8);
            uint4 w8 = *(const uint4*)(wsrc + (size_t)b * 1024 + kq + part * 8);
            const unsigned short* d16 = (const unsigned short*)&d8;
            const unsigned short* w16 = (const unsigned short*)&w8;
            uint4 o; unsigned short* o16 = (unsigned short*)&o;
#pragma unroll
            for (int j = 0; j < 8; j++) {
                float dv = bf2f(d16[j]), wv = bf2f(w16[j]);
                float r = (q < 2) ? dv * wv : fabsf(dv - wv);
                o16[j] = f2bf_trunc(r);
            }
            *(uint4*)&As[row][part * 8] = o;
        }
        // B: W1t rows n0..n0+255
#pragma unroll
        for (int rep = 0; rep < 4; ++rep) {
            int c = tid + rep * 256;
            int n = c >> 2, part = c & 3;
            *(uint4*)&Bs[n][part * 8] =
                *(const uint4*)(W1t + (size_t)(n0 + n) * 4096 + kt * 32 + part * 8);
        }
        __syncthreads();
        bf16x8 af[4], bfr[8];
#pragma unroll
        for (int im = 0; im < 4; im++) af[im] = ldfrag(&As[qm * 64 + im * 16 + nlane][k0]);
#pragma unroll
        for (int in = 0; in < 8; in++) bfr[in] = ldfrag(&Bs[qn * 128 + in * 16 + nlane][k0]);
#pragma unroll
        for (int im = 0; im < 4; im++)
#pragma unroll
            for (int in = 0; in < 8; in++)
                acc[im][in] = __builtin_amdgcn_mfma_f32_16x16x32_bf16(af[im], bfr[in], acc[im][in], 0, 0, 0);
        __syncthreads();
    }
    // epilogue: tanh(+b1)*W2, reduce over cols
    if (tid < 128) red[tid] = 0.f;
    __syncthreads();
    float b1v[8], w2v[8];
#pragma unroll
    for (int in = 0; in < 8; in++) {
        int col = n0 + qn * 128 + in * 16 + nlane;
        b1v[in] = b1[col]; w2v[in] = W2[col];
    }
#pragma unroll
    for (int im = 0; im < 4; im++)
#pragma unroll
        for (int i = 0; i < 4; i++) {
            float s = 0.f;
#pragma unroll
            for (int in = 0; in < 8; in++) s += ftanh(acc[im][in][i] + b1v[in]) * w2v[in];
            s += __shfl_xor(s, 1); s += __shfl_xor(s, 2); s += __shfl_xor(s, 4); s += __shfl_xor(s, 8);
            if (nlane == 0) atomicAdd(&red[qm * 64 + im * 16 + quad * 4 + i], s);
        }
    __syncthreads();
    if (tid < 128) Zpart[(size_t)(r0 + tid) * 4 + nt] = red[tid];
}

// ---------------- GEMM2: [Dr|Dw] = D @ [Wr|Wx] + [br|bx], store bf16 transposed (t,b,:) ----------------
// grid (8, 128); tile 128 x 256; K=1024
__global__ __launch_bounds__(256, 2) void k_gemm2(
    const unsigned short* __restrict__ Dc, const unsigned short* __restrict__ Wrxt,
    const float* __restrict__ br, const float* __restrict__ bx,
    unsigned short* __restrict__ Drwt) {
    __shared__ alignas(16) unsigned short As[128][40];
    __shared__ alignas(16) unsigned short Bs[256][40];
    const int tid = threadIdx.x;
    const int nt = blockIdx.x, mt = blockIdx.y;
    const int r0 = mt * 128, n0 = nt * 256;
    const int lane = tid & 63, wid = tid >> 6;
    const int qm = wid & 1, qn = wid >> 1;
    const int nlane = lane & 15, quad = lane >> 4, k0 = quad * 8;

    f32x4 acc[4][8];
#pragma unroll
    for (int im = 0; im < 4; im++)
#pragma unroll
        for (int in = 0; in < 8; in++) acc[im][in] = (f32x4){0.f, 0.f, 0.f, 0.f};

    for (int kt = 0; kt < 32; ++kt) {
#pragma unroll
        for (int rep = 0; rep < 2; ++rep) {
            int c = tid + rep * 256;
            int row = c >> 2, part = c & 3;
            *(uint4*)&As[row][part * 8] =
                *(const uint4*)(Dc + (size_t)(r0 + row) * 1024 + kt * 32 + part * 8);
        }
#pragma unroll
        for (int rep = 0; rep < 4; ++rep) {
            int c = tid + rep * 256;
            int n = c >> 2, part = c & 3;
            *(uint4*)&Bs[n][part * 8] =
                *(const uint4*)(Wrxt + (size_t)(n0 + n) * 1024 + kt * 32 + part * 8);
        }
        __syncthreads();
        bf16x8 af[4], bfr[8];
#pragma unroll
        for (int im = 0; im < 4; im++) af[im] = ldfrag(&As[qm * 64 + im * 16 + nlane][k0]);
#pragma unroll
        for (int in = 0; in < 8; in++) bfr[in] = ldfrag(&Bs[qn * 128 + in * 16 + nlane][k0]);
#pragma unroll
        for (int im = 0; im < 4; im++)
#pragma unroll
            for (int in = 0; in < 8; in++)
                acc[im][in] = __builtin_amdgcn_mfma_f32_16x16x32_bf16(af[im], bfr[in], acc[im][in], 0, 0, 0);
        __syncthreads();
    }
    float bias[8];
#pragma unroll
    for (int in = 0; in < 8; in++) {
        int col = n0 + qn * 128 + in * 16 + nlane;
        bias[in] = (col < 1024) ? br[col] : bx[col - 1024];
    }
#pragma unroll
    for (int im = 0; im < 4; im++)
#pragma unroll
        for (int i = 0; i < 4; i++) {
            int r = r0 + qm * 64 + im * 16 + quad * 4 + i;
            int bb = r >> 8, t = r & 255;
            unsigned short* dp = Drwt + ((size_t)t * 64 + bb) * 2048;
#pragma unroll
            for (int in = 0; in < 8; in++) {
                int col = n0 + qn * 128 + in * 16 + nlane;
                dp[col] = f2bf(acc[im][in][i] + bias[in]);
            }
        }
}

// ---------------- softmax over S per batch ----------------
__global__ __launch_bounds__(256) void k_softmax(const float* __restrict__ Zpart,
                                                 float* __restrict__ Gt) {
    int b = blockIdx.x, s = threadIdx.x;
    const float* zp = Zpart + ((size_t)b * 256 + s) * 4;
    float l = zp[0] + zp[1] + zp[2] + zp[3];
    __shared__ float sm[4], ss[4];
    int lane = s & 63, wid = s >> 6;
    float m = l;
#pragma unroll
    for (int o = 32; o; o >>= 1) m = fmaxf(m, __shfl_xor(m, o));
    if (lane == 0) sm[wid] = m;
    __syncthreads();
    m = fmaxf(fmaxf(sm[0], sm[1]), fmaxf(sm[2], sm[3]));
    float e = __expf(l - m);
    float sum = e;
#pragma unroll
    for (int o = 32; o; o >>= 1) sum += __shfl_xor(sum, o);
    if (lane == 0) ss[wid] = sum;
    __syncthreads();
    sum = ss[0] + ss[1] + ss[2] + ss[3];
    Gt[(size_t)s * 64 + b] = e / sum;
}

// ---------------- scan: 64 persistent WGs, per-step device barrier ----------------
__global__ __launch_bounds__(256, 1) void k_scan(
    const unsigned short* __restrict__ Urt, const unsigned short* __restrict__ Ut,
    const unsigned short* __restrict__ Drwt, const float* __restrict__ Gt,
    const float* __restrict__ bur, const float* __restrict__ bu,
    unsigned short* __restrict__ hb0, unsigned short* __restrict__ hb1,
    unsigned short* __restrict__ Cc, float* __restrict__ hs, int* __restrict__ cnt) {
    const int w = blockIdx.x;                 // column slice
    const int tid = threadIdx.x, lane = tid & 63, wv = tid >> 6;
    const int nlane = lane & 15, quad = lane >> 4;
    const int n = w * 16 + nlane;             // output column
    const int m0 = wv * 16;                   // batch-row base of this wave
    const int brow = m0 + quad * 4;           // +i = batch row of acc elem i

    // preload weight slices into registers (persist across all 256 steps)
    bf16x8 BU[32], BW[32];
#pragma unroll
    for (int ks = 0; ks < 32; ks++) {
        int kk = ks * 32 + quad * 8;
        BU[ks] = ldfrag(Urt + (size_t)n * 1024 + kk);
        BW[ks] = ldfrag(Ut + (size_t)n * 1024 + kk);
    }
    const float burj = bur[n], buj = bu[n];
    float hst[4] = {0.f, 0.f, 0.f, 0.f};      // fp32 state for owned elements
    const unsigned short* hcur = hb0;
    unsigned short* hnxt = hb1;

#pragma unroll 1
    for (int t = 0; t < 256; t++) {
        // prefetch step inputs (independent of h)
        float dr[4], dw[4], g[4];
#pragma unroll
        for (int i = 0; i < 4; i++) {
            int r = brow + i;
            const unsigned short* dp = Drwt + ((size_t)t * 64 + r) * 2048;
            dr[i] = bf2f(dp[n]);
            dw[i] = bf2f(dp[1024 + n]);
            g[i] = Gt[t * 64 + r];
        }
        f32x4 aU0 = {0.f,0.f,0.f,0.f}, aU1 = {0.f,0.f,0.f,0.f};
        f32x4 aW0 = {0.f,0.f,0.f,0.f}, aW1 = {0.f,0.f,0.f,0.f};
        const unsigned short* hrow = hcur + (size_t)(m0 + nlane) * 1024 + quad * 8;
#pragma unroll
        for (int ks = 0; ks < 16; ks++) {
            bf16x8 a0 = ldfrag(hrow + (2 * ks) * 32);
            bf16x8 a1 = ldfrag(hrow + (2 * ks + 1) * 32);
            aU0 = __builtin_amdgcn_mfma_f32_16x16x32_bf16(a0, BU[2 * ks], aU0, 0, 0, 0);
            aW0 = __builtin_amdgcn_mfma_f32_16x16x32_bf16(a0, BW[2 * ks], aW0, 0, 0, 0);
            aU1 = __builtin_amdgcn_mfma_f32_16x16x32_bf16(a1, BU[2 * ks + 1], aU1, 0, 0, 0);
            aW1 = __builtin_amdgcn_mfma_f32_16x16x32_bf16(a1, BW[2 * ks + 1], aW1, 0, 0, 0);
        }
#pragma unroll
        for (int i = 0; i < 4; i++) {
            float r = fsigm(dr[i] + aU0[i] + aU1[i] + burj);
            float ht = ftanh(dw[i] + r * (aW0[i] + aW1[i] + buj));
            float hn = g[i] * ht + (1.f - g[i]) * hst[i];
            hst[i] = hn;
            int row = brow + i;
            hnxt[(size_t)row * 1024 + n] = f2bf(hn);
            hs[((size_t)row * 256 + t) * 1024 + n] = hn;
        }
        if (t == 255) {
#pragma unroll
            for (int i = 0; i < 4; i++) Cc[(size_t)(brow + i) * 1024 + n] = f2bf(hst[i]);
        }
        // device-scope barrier
        __threadfence();
        __syncthreads();
        if (tid == 0) {
            __hip_atomic_fetch_add(cnt, 1, __ATOMIC_RELEASE, __HIP_MEMORY_SCOPE_AGENT);
            int target = (t + 1) * 64;
            while (__hip_atomic_load(cnt, __ATOMIC_ACQUIRE, __HIP_MEMORY_SCOPE_AGENT) < target)
                __builtin_amdgcn_s_sleep(1);
        }
        __syncthreads();
        __threadfence();
        const unsigned short* tmp = hcur; hcur = hnxt; hnxt = (unsigned short*)tmp;
    }
}

// ---------------- final: next_mem = relu([prev|C|Q] @ Wm + bm) ----------------
// grid 8; tile 64 x 128; K=3072
__global__ __launch_bounds__(256) void k_final(
    const unsigned short* __restrict__ Pc, const unsigned short* __restrict__ Cc,
    const unsigned short* __restrict__ Qc, const unsigned short* __restrict__ Wmt,
    const float* __restrict__ bm, float* __restrict__ outp) {
    __shared__ alignas(16) unsigned short As[64][40];
    __shared__ alignas(16) unsigned short Bs[128][40];
    const int tid = threadIdx.x;
    const int n0 = blockIdx.x * 128;
    const int lane = tid & 63, wid = tid >> 6;
    const int nlane = lane & 15, quad = lane >> 4, k0 = quad * 8;
    f32x4 acc[4][2];
#pragma unroll
    for (int im = 0; im < 4; im++) { acc[im][0] = (f32x4){0.f,0.f,0.f,0.f}; acc[im][1] = (f32x4){0.f,0.f,0.f,0.f}; }

    for (int kt = 0; kt < 96; ++kt) {
        {
            int row = tid >> 2, part = tid & 3;
            int kk = kt * 32 + part * 8;
            int sec = kk >> 10, off = kk & 1023;
            const unsigned short* sp = (sec == 0) ? Pc : (sec == 1) ? Cc : Qc;
            *(uint4*)&As[row][part * 8] = *(const uint4*)(sp + (size_t)row * 1024 + off);
        }
#pragma unroll
        for (int rep = 0; rep < 2; rep++) {
            int c = tid + rep * 256;
            int n = c >> 2, part = c & 3;
            *(uint4*)&Bs[n][part * 8] =
                *(const uint4*)(Wmt + (size_t)(n0 + n) * 3072 + kt * 32 + part * 8);
        }
        __syncthreads();
        bf16x8 af[4], bfr[2];
#pragma unroll
        for (int im = 0; im < 4; im++) af[im] = ldfrag(&As[im * 16 + nlane][k0]);
#pragma unroll
        for (int in = 0; in < 2; in++) bfr[in] = ldfrag(&Bs[wid * 32 + in * 16 + nlane][k0]);
#pragma unroll
        for (int im = 0; im < 4; im++)
#pragma unroll
            for (int in = 0; in < 2; in++)
                acc[im][in] = __builtin_amdgcn_mfma_f32_16x16x32_bf16(af[im], bfr[in], acc[im][in], 0, 0, 0);
        __syncthreads();
    }
#pragma unroll
    for (int im = 0; im < 4; im++)
#pragma unroll
        for (int i = 0; i < 4; i++)
#pragma unroll
            for (int in = 0; in < 2; in++) {
                int row = im * 16 + quad * 4 + i;
                int col = n0 + wid * 32 + in * 16 + nlane;
                float v = acc[im][in][i] + bm[col];
                outp[(size_t)row * 1024 + col] = fmaxf(v, 0.f);
            }
}

// ---------------- launch ----------------
extern "C" void kernel_launch(void* const* d_in, const int* in_sizes, int n_in,
                              void* d_out, int out_size, void* d_ws, size_t ws_size,
                              hipStream_t stream) {
    const float* D  = (const float*)d_in[0];
    const float* Q  = (const float*)d_in[1];
    const float* P  = (const float*)d_in[2];
    const float* Wr = (const float*)d_in[3];
    const float* br = (const float*)d_in[4];
    const float* Ur = (const float*)d_in[5];
    const float* bur= (const float*)d_in[6];
    const float* Wx = (const float*)d_in[7];
    const float* bx = (const float*)d_in[8];
    const float* U  = (const float*)d_in[9];
    const float* bu = (const float*)d_in[10];
    const float* W1 = (const float*)d_in[11];
    const float* b1 = (const float*)d_in[12];
    const float* W2 = (const float*)d_in[13];
    const float* Wm = (const float*)d_in[15];
    const float* bm = (const float*)d_in[16];

    char* ws = (char*)d_ws;
    int* cnt            = (int*)ws;                                 // 4 B (pad 256)
    unsigned short* hb0 = (unsigned short*)(ws + 256);              // 128 KiB
    unsigned short* hb1 = (unsigned short*)(ws + 131328);           // 128 KiB
    unsigned short* Dc  = (unsigned short*)(ws + 262400);           // 32 MiB
    unsigned short* Qc  = (unsigned short*)(ws + 33816832);
    unsigned short* Pc  = (unsigned short*)(ws + 33947904);
    unsigned short* W1t = (unsigned short*)(ws + 34078976);         // (1024,4096)
    unsigned short* Wrxt= (unsigned short*)(ws + 42467584);         // (2048,1024)
    unsigned short* Urt = (unsigned short*)(ws + 46661888);         // (1024,1024)
    unsigned short* Utb = (unsigned short*)(ws + 48759040);         // (1024,1024)
    unsigned short* Wmt = (unsigned short*)(ws + 50856192);         // (1024,3072)
    unsigned short* Cc  = (unsigned short*)(ws + 57147648);
    float* Zpart        = (float*)(ws + 57278720);                  // (16384,4)
    float* Gt           = (float*)(ws + 57540864);                  // (256,64)
    unsigned short* Drwt= (unsigned short*)(ws + 57606400);         // (256,64,2048) bf16

    float* outNM = (float*)d_out;
    float* hsOut = (float*)d_out + 65536;

    hipMemsetAsync(ws, 0, 262400, stream);  // counter + h0 = zeros

    k_cast<<<16384, 256, 0, stream>>>(D, Dc, 4194304);
    k_cast<<<64, 256, 0, stream>>>(Q, Qc, 16384);
    k_cast<<<64, 256, 0, stream>>>(P, Pc, 16384);
    k_transpose_bf16<<<dim3(32, 128), 256, 0, stream>>>(W1, W1t, 4096, 1024);
    k_transpose_bf16<<<dim3(32, 32), 256, 0, stream>>>(Wr, Wrxt, 1024, 1024);
    k_transpose_bf16<<<dim3(32, 32), 256, 0, stream>>>(Wx, Wrxt + (size_t)1024 * 1024, 1024, 1024);
    k_transpose_bf16<<<dim3(32, 32), 256, 0, stream>>>(Ur, Urt, 1024, 1024);
    k_transpose_bf16<<<dim3(32, 32), 256, 0, stream>>>(U, Utb, 1024, 1024);
    k_transpose_bf16<<<dim3(32, 96), 256, 0, stream>>>(Wm, Wmt, 3072, 1024);

    k_gemm1<<<dim3(4, 128), 256, 0, stream>>>(Dc, Qc, Pc, W1t, b1, W2, Zpart);
    k_gemm2<<<dim3(8, 128), 256, 0, stream>>>(Dc, Wrxt, br, bx, Drwt);
    k_softmax<<<64, 256, 0, stream>>>(Zpart, Gt);
    k_scan<<<64, 256, 0, stream>>>(Urt, Utb, Drwt, Gt, bur, bu, hb0, hb1, Cc, hsOut, cnt);
    k_final<<<8, 256, 0, stream>>>(Pc, Cc, Qc, Wmt, bm, outNM);
}

// Round 2
// 3188.937 us; speedup vs baseline: 1.8839x; 1.8839x over previous
//
#include <hip/hip_runtime.h>
#include <stdint.h>

typedef __bf16 bf16x8 __attribute__((ext_vector_type(8)));
typedef float f32x4 __attribute__((ext_vector_type(4)));

__device__ __forceinline__ float bf2f(unsigned short h) {
    union { unsigned int u; float f; } v; v.u = ((unsigned int)h) << 16; return v.f;
}
__device__ __forceinline__ unsigned short f2bf(float f) {  // RNE
    union { float f; unsigned int u; } v; v.f = f;
    unsigned int r = (v.u + 0x7FFFu + ((v.u >> 16) & 1u)) >> 16;
    return (unsigned short)r;
}
__device__ __forceinline__ unsigned short f2bf_trunc(float f) {
    union { float f; unsigned int u; } v; v.f = f;
    return (unsigned short)(v.u >> 16);
}
__device__ __forceinline__ bf16x8 ldfrag(const unsigned short* p) {
    uint4 u = *(const uint4*)p; return __builtin_bit_cast(bf16x8, u);
}
// coherent (MALL-direct) 16B fragment load as 2x8B relaxed agent atomics
__device__ __forceinline__ bf16x8 ldfrag_coh(const unsigned short* p) {
    union { unsigned long long q[2]; bf16x8 v; } u;
    u.q[0] = __hip_atomic_load((const unsigned long long*)p, __ATOMIC_RELAXED, __HIP_MEMORY_SCOPE_AGENT);
    u.q[1] = __hip_atomic_load((const unsigned long long*)(p + 4), __ATOMIC_RELAXED, __HIP_MEMORY_SCOPE_AGENT);
    return u.v;
}
__device__ __forceinline__ float fsigm(float x) { return 1.f / (1.f + __expf(-x)); }
__device__ __forceinline__ float ftanh(float x) { float e = __expf(2.f * x); return 1.f - 2.f / (e + 1.f); }

// ---------------- casts / transposes ----------------
__global__ __launch_bounds__(256) void k_cast(const float* __restrict__ src,
                                              unsigned short* __restrict__ dst, int n4) {
    int i = blockIdx.x * 256 + threadIdx.x;
    if (i >= n4) return;
    float4 v = ((const float4*)src)[i];
    union { unsigned short s[4]; uint2 u; } o;
    o.s[0] = f2bf(v.x); o.s[1] = f2bf(v.y); o.s[2] = f2bf(v.z); o.s[3] = f2bf(v.w);
    ((uint2*)dst)[i] = o.u;
}

// src (R,C) fp32 -> dst (C,R) bf16
__global__ __launch_bounds__(256) void k_transpose_bf16(const float* __restrict__ src,
                                                        unsigned short* __restrict__ dst,
                                                        int R, int C) {
    __shared__ float tile[32][33];
    int tc = threadIdx.x & 31, tr = threadIdx.x >> 5;  // tr 0..7
    int r0 = blockIdx.y * 32, c0 = blockIdx.x * 32;
#pragma unroll
    for (int p = 0; p < 4; p++) tile[tr + p * 8][tc] = src[(size_t)(r0 + tr + p * 8) * C + c0 + tc];
    __syncthreads();
#pragma unroll
    for (int p = 0; p < 4; p++) dst[(size_t)(c0 + tr + p * 8) * R + r0 + tc] = f2bf(tile[tc][tr + p * 8]);
}

// ---------------- GEMM1: Zs partials (z on the fly, fused tanh*W2 reduce) ----------------
// grid (4, 128); tile 128(M) x 256(N); K=4096
__global__ __launch_bounds__(256, 2) void k_gemm1(
    const unsigned short* __restrict__ Dc, const unsigned short* __restrict__ Qc,
    const unsigned short* __restrict__ Pc, const unsigned short* __restrict__ W1t,
    const float* __restrict__ b1, const float* __restrict__ W2, float* __restrict__ Zpart) {
    __shared__ alignas(16) unsigned short As[128][40];
    __shared__ alignas(16) unsigned short Bs[256][40];
    __shared__ float red[128];
    const int tid = threadIdx.x;
    const int nt = blockIdx.x, mt = blockIdx.y;
    const int r0 = mt * 128, n0 = nt * 256, b = r0 >> 8;
    const int lane = tid & 63, wid = tid >> 6;
    const int qm = wid & 1, qn = wid >> 1;
    const int nlane = lane & 15, quad = lane >> 4, k0 = quad * 8;

    f32x4 acc[4][8];
#pragma unroll
    for (int im = 0; im < 4; im++)
#pragma unroll
        for (int in = 0; in < 8; in++) acc[im][in] = (f32x4){0.f, 0.f, 0.f, 0.f};

    for (int kt = 0; kt < 128; ++kt) {
        const int q = kt >> 5;               // quarter of z
        const int kq = (kt & 31) * 32;       // k within quarter
        const unsigned short* wsrc = (q & 1) ? Pc : Qc;
        // A: build z tile (128 x 32)
#pragma unroll
        for (int rep = 0; rep < 2; ++rep) {
            int c = tid + rep * 256;
            int row = c >> 2, part = c & 3;
            uint4 d8 = *(const uint4*)(Dc + (size_t)(r0 + row) * 1024 + kq + part * 8);
            uint4 w8 = *(const uint4*)(wsrc + (size_t)b * 1024 + kq + part * 8);
            const unsigned short* d16 = (const unsigned short*)&d8;
            const unsigned short* w16 = (const unsigned short*)&w8;
            uint4 o; unsigned short* o16 = (unsigned short*)&o;
#pragma unroll
            for (int j = 0; j < 8; j++) {
                float dv = bf2f(d16[j]), wv = bf2f(w16[j]);
                float r = (q < 2) ? dv * wv : fabsf(dv - wv);
                o16[j] = f2bf_trunc(r);
            }
            *(uint4*)&As[row][part * 8] = o;
        }
        // B: W1t rows n0..n0+255
#pragma unroll
        for (int rep = 0; rep < 4; ++rep) {
            int c = tid + rep * 256;
            int n = c >> 2, part = c & 3;
            *(uint4*)&Bs[n][part * 8] =
                *(const uint4*)(W1t + (size_t)(n0 + n) * 4096 + kt * 32 + part * 8);
        }
        __syncthreads();
        bf16x8 af[4], bfr[8];
#pragma unroll
        for (int im = 0; im < 4; im++) af[im] = ldfrag(&As[qm * 64 + im * 16 + nlane][k0]);
#pragma unroll
        for (int in = 0; in < 8; in++) bfr[in] = ldfrag(&Bs[qn * 128 + in * 16 + nlane][k0]);
#pragma unroll
        for (int im = 0; im < 4; im++)
#pragma unroll
            for (int in = 0; in < 8; in++)
                acc[im][in] = __builtin_amdgcn_mfma_f32_16x16x32_bf16(af[im], bfr[in], acc[im][in], 0, 0, 0);
        __syncthreads();
    }
    // epilogue: tanh(+b1)*W2, reduce over cols
    if (tid < 128) red[tid] = 0.f;
    __syncthreads();
    float b1v[8], w2v[8];
#pragma unroll
    for (int in = 0; in < 8; in++) {
        int col = n0 + qn * 128 + in * 16 + nlane;
        b1v[in] = b1[col]; w2v[in] = W2[col];
    }
#pragma unroll
    for (int im = 0; im < 4; im++)
#pragma unroll
        for (int i = 0; i < 4; i++) {
            float s = 0.f;
#pragma unroll
            for (int in = 0; in < 8; in++) s += ftanh(acc[im][in][i] + b1v[in]) * w2v[in];
            s += __shfl_xor(s, 1); s += __shfl_xor(s, 2); s += __shfl_xor(s, 4); s += __shfl_xor(s, 8);
            if (nlane == 0) atomicAdd(&red[qm * 64 + im * 16 + quad * 4 + i], s);
        }
    __syncthreads();
    if (tid < 128) Zpart[(size_t)(r0 + tid) * 4 + nt] = red[tid];
}

// ---------------- GEMM2: [Dr|Dw] = D @ [Wr|Wx] + [br|bx], store bf16 transposed (t,b,:) ----------------
// grid (8, 128); tile 128 x 256; K=1024
__global__ __launch_bounds__(256, 2) void k_gemm2(
    const unsigned short* __restrict__ Dc, const unsigned short* __restrict__ Wrxt,
    const float* __restrict__ br, const float* __restrict__ bx,
    unsigned short* __restrict__ Drwt) {
    __shared__ alignas(16) unsigned short As[128][40];
    __shared__ alignas(16) unsigned short Bs[256][40];
    const int tid = threadIdx.x;
    const int nt = blockIdx.x, mt = blockIdx.y;
    const int r0 = mt * 128, n0 = nt * 256;
    const int lane = tid & 63, wid = tid >> 6;
    const int qm = wid & 1, qn = wid >> 1;
    const int nlane = lane & 15, quad = lane >> 4, k0 = quad * 8;

    f32x4 acc[4][8];
#pragma unroll
    for (int im = 0; im < 4; im++)
#pragma unroll
        for (int in = 0; in < 8; in++) acc[im][in] = (f32x4){0.f, 0.f, 0.f, 0.f};

    for (int kt = 0; kt < 32; ++kt) {
#pragma unroll
        for (int rep = 0; rep < 2; ++rep) {
            int c = tid + rep * 256;
            int row = c >> 2, part = c & 3;
            *(uint4*)&As[row][part * 8] =
                *(const uint4*)(Dc + (size_t)(r0 + row) * 1024 + kt * 32 + part * 8);
        }
#pragma unroll
        for (int rep = 0; rep < 4; ++rep) {
            int c = tid + rep * 256;
            int n = c >> 2, part = c & 3;
            *(uint4*)&Bs[n][part * 8] =
                *(const uint4*)(Wrxt + (size_t)(n0 + n) * 1024 + kt * 32 + part * 8);
        }
        __syncthreads();
        bf16x8 af[4], bfr[8];
#pragma unroll
        for (int im = 0; im < 4; im++) af[im] = ldfrag(&As[qm * 64 + im * 16 + nlane][k0]);
#pragma unroll
        for (int in = 0; in < 8; in++) bfr[in] = ldfrag(&Bs[qn * 128 + in * 16 + nlane][k0]);
#pragma unroll
        for (int im = 0; im < 4; im++)
#pragma unroll
            for (int in = 0; in < 8; in++)
                acc[im][in] = __builtin_amdgcn_mfma_f32_16x16x32_bf16(af[im], bfr[in], acc[im][in], 0, 0, 0);
        __syncthreads();
    }
    float bias[8];
#pragma unroll
    for (int in = 0; in < 8; in++) {
        int col = n0 + qn * 128 + in * 16 + nlane;
        bias[in] = (col < 1024) ? br[col] : bx[col - 1024];
    }
#pragma unroll
    for (int im = 0; im < 4; im++)
#pragma unroll
        for (int i = 0; i < 4; i++) {
            int r = r0 + qm * 64 + im * 16 + quad * 4 + i;
            int bb = r >> 8, t = r & 255;
            unsigned short* dp = Drwt + ((size_t)t * 64 + bb) * 2048;
#pragma unroll
            for (int in = 0; in < 8; in++) {
                int col = n0 + qn * 128 + in * 16 + nlane;
                dp[col] = f2bf(acc[im][in][i] + bias[in]);
            }
        }
}

// ---------------- softmax over S per batch ----------------
__global__ __launch_bounds__(256) void k_softmax(const float* __restrict__ Zpart,
                                                 float* __restrict__ Gt) {
    int b = blockIdx.x, s = threadIdx.x;
    const float* zp = Zpart + ((size_t)b * 256 + s) * 4;
    float l = zp[0] + zp[1] + zp[2] + zp[3];
    __shared__ float sm[4], ss[4];
    int lane = s & 63, wid = s >> 6;
    float m = l;
#pragma unroll
    for (int o = 32; o; o >>= 1) m = fmaxf(m, __shfl_xor(m, o));
    if (lane == 0) sm[wid] = m;
    __syncthreads();
    m = fmaxf(fmaxf(sm[0], sm[1]), fmaxf(sm[2], sm[3]));
    float e = __expf(l - m);
    float sum = e;
#pragma unroll
    for (int o = 32; o; o >>= 1) sum += __shfl_xor(sum, o);
    if (lane == 0) ss[wid] = sum;
    __syncthreads();
    sum = ss[0] + ss[1] + ss[2] + ss[3];
    Gt[(size_t)s * 64 + b] = e / sum;
}

// ---------------- scan: 64 persistent WGs, flag-array barrier, NO cache-maintenance ops ----------------
// h exchange: stores = relaxed agent atomics (sc1 write-through to MALL),
// loads = relaxed agent 8B atomics (bypass L1/L2). Barrier: per-WG monotone
// flags + wave-0 ballot poll, all relaxed => no buffer_wbl2 / buffer_inv.
__global__ __launch_bounds__(256, 1) void k_scan(
    const unsigned short* __restrict__ Urt, const unsigned short* __restrict__ Ut,
    const unsigned short* __restrict__ Drwt, const float* __restrict__ Gt,
    const float* __restrict__ bur, const float* __restrict__ bu,
    unsigned short* __restrict__ hb0, unsigned short* __restrict__ hb1,
    unsigned short* __restrict__ Cc, float* __restrict__ hs, int* __restrict__ flags) {
    const int w = blockIdx.x;                 // column slice
    const int tid = threadIdx.x, lane = tid & 63, wv = tid >> 6;
    const int nlane = lane & 15, quad = lane >> 4;
    const int n = w * 16 + nlane;             // output column
    const int m0 = wv * 16;                   // batch-row base of this wave
    const int brow = m0 + quad * 4;           // +i = batch row of acc elem i

    // preload weight slices into registers (persist across all 256 steps)
    bf16x8 BU[32], BW[32];
#pragma unroll
    for (int ks = 0; ks < 32; ks++) {
        int kk = ks * 32 + quad * 8;
        BU[ks] = ldfrag(Urt + (size_t)n * 1024 + kk);
        BW[ks] = ldfrag(Ut + (size_t)n * 1024 + kk);
    }
    const float burj = bur[n], buj = bu[n];
    float hst[4] = {0.f, 0.f, 0.f, 0.f};      // fp32 state for owned elements
    const unsigned short* hcur = hb0;
    unsigned short* hnxt = hb1;

    // prefetch step-0 inputs
    float dr[4], dw[4], g[4];
#pragma unroll
    for (int i = 0; i < 4; i++) {
        int r = brow + i;
        const unsigned short* dp = Drwt + ((size_t)r) * 2048;
        dr[i] = bf2f(dp[n]);
        dw[i] = bf2f(dp[1024 + n]);
        g[i] = Gt[r];
    }

#pragma unroll 1
    for (int t = 0; t < 256; t++) {
        f32x4 aU0 = {0.f,0.f,0.f,0.f}, aU1 = {0.f,0.f,0.f,0.f};
        f32x4 aW0 = {0.f,0.f,0.f,0.f}, aW1 = {0.f,0.f,0.f,0.f};
        const unsigned short* hrow = hcur + (size_t)(m0 + nlane) * 1024 + quad * 8;
#pragma unroll
        for (int ks = 0; ks < 16; ks++) {
            bf16x8 a0 = ldfrag_coh(hrow + (2 * ks) * 32);
            bf16x8 a1 = ldfrag_coh(hrow + (2 * ks + 1) * 32);
            aU0 = __builtin_amdgcn_mfma_f32_16x16x32_bf16(a0, BU[2 * ks], aU0, 0, 0, 0);
            aW0 = __builtin_amdgcn_mfma_f32_16x16x32_bf16(a0, BW[2 * ks], aW0, 0, 0, 0);
            aU1 = __builtin_amdgcn_mfma_f32_16x16x32_bf16(a1, BU[2 * ks + 1], aU1, 0, 0, 0);
            aW1 = __builtin_amdgcn_mfma_f32_16x16x32_bf16(a1, BW[2 * ks + 1], aW1, 0, 0, 0);
        }
#pragma unroll
        for (int i = 0; i < 4; i++) {
            float r = fsigm(dr[i] + aU0[i] + aU1[i] + burj);
            float ht = ftanh(dw[i] + r * (aW0[i] + aW1[i] + buj));
            float hn = g[i] * ht + (1.f - g[i]) * hst[i];
            hst[i] = hn;
            int row = brow + i;
            // coherent write-through store (no L2 flush needed for visibility)
            __hip_atomic_store(&hnxt[(size_t)row * 1024 + n], f2bf(hn),
                               __ATOMIC_RELAXED, __HIP_MEMORY_SCOPE_AGENT);
            hs[((size_t)row * 256 + t) * 1024 + n] = hn;
        }
        if (t == 255) {
#pragma unroll
            for (int i = 0; i < 4; i++) Cc[(size_t)(brow + i) * 1024 + n] = f2bf(hst[i]);
        }
        // all waves' sc1 h-stores drained (syncthreads waits vmcnt(0) per wave)
        __syncthreads();
        // prefetch next step's inputs BEFORE the poll so latency hides under it
        float drn[4], dwn[4], gn[4];
        if (t < 255) {
#pragma unroll
            for (int i = 0; i < 4; i++) {
                int r = brow + i;
                const unsigned short* dp = Drwt + ((size_t)(t + 1) * 64 + r) * 2048;
                drn[i] = bf2f(dp[n]);
                dwn[i] = bf2f(dp[1024 + n]);
                gn[i] = Gt[(t + 1) * 64 + r];
            }
            if (tid == 0)
                __hip_atomic_store(&flags[w], t + 1, __ATOMIC_RELAXED, __HIP_MEMORY_SCOPE_AGENT);
            if (tid < 64) {
                const int tgt = t + 1;
                while (true) {
                    int v = __hip_atomic_load(&flags[tid], __ATOMIC_RELAXED, __HIP_MEMORY_SCOPE_AGENT);
                    if (__ballot(v >= tgt) == ~0ull) break;
                }
            }
        }
        __syncthreads();
#pragma unroll
        for (int i = 0; i < 4; i++) { dr[i] = drn[i]; dw[i] = dwn[i]; g[i] = gn[i]; }
        const unsigned short* tmp = hcur; hcur = hnxt; hnxt = (unsigned short*)tmp;
    }
}

// ---------------- final: next_mem = relu([prev|C|Q] @ Wm + bm) ----------------
// grid 8; tile 64 x 128; K=3072
__global__ __launch_bounds__(256) void k_final(
    const unsigned short* __restrict__ Pc, const unsigned short* __restrict__ Cc,
    const unsigned short* __restrict__ Qc, const unsigned short* __restrict__ Wmt,
    const float* __restrict__ bm, float* __restrict__ outp) {
    __shared__ alignas(16) unsigned short As[64][40];
    __shared__ alignas(16) unsigned short Bs[128][40];
    const int tid = threadIdx.x;
    const int n0 = blockIdx.x * 128;
    const int lane = tid & 63, wid = tid >> 6;
    const int nlane = lane & 15, quad = lane >> 4, k0 = quad * 8;
    f32x4 acc[4][2];
#pragma unroll
    for (int im = 0; im < 4; im++) { acc[im][0] = (f32x4){0.f,0.f,0.f,0.f}; acc[im][1] = (f32x4){0.f,0.f,0.f,0.f}; }

    for (int kt = 0; kt < 96; ++kt) {
        {
            int row = tid >> 2, part = tid & 3;
            int kk = kt * 32 + part * 8;
            int sec = kk >> 10, off = kk & 1023;
            const unsigned short* sp = (sec == 0) ? Pc : (sec == 1) ? Cc : Qc;
            *(uint4*)&As[row][part * 8] = *(const uint4*)(sp + (size_t)row * 1024 + off);
        }
#pragma unroll
        for (int rep = 0; rep < 2; rep++) {
            int c = tid + rep * 256;
            int n = c >> 2, part = c & 3;
            *(uint4*)&Bs[n][part * 8] =
                *(const uint4*)(Wmt + (size_t)(n0 + n) * 3072 + kt * 32 + part * 8);
        }
        __syncthreads();
        bf16x8 af[4], bfr[2];
#pragma unroll
        for (int im = 0; im < 4; im++) af[im] = ldfrag(&As[im * 16 + nlane][k0]);
#pragma unroll
        for (int in = 0; in < 2; in++) bfr[in] = ldfrag(&Bs[wid * 32 + in * 16 + nlane][k0]);
#pragma unroll
        for (int im = 0; im < 4; im++)
#pragma unroll
            for (int in = 0; in < 2; in++)
                acc[im][in] = __builtin_amdgcn_mfma_f32_16x16x32_bf16(af[im], bfr[in], acc[im][in], 0, 0, 0);
        __syncthreads();
    }
#pragma unroll
    for (int im = 0; im < 4; im++)
#pragma unroll
        for (int i = 0; i < 4; i++)
#pragma unroll
            for (int in = 0; in < 2; in++) {
                int row = im * 16 + quad * 4 + i;
                int col = n0 + wid * 32 + in * 16 + nlane;
                float v = acc[im][in][i] + bm[col];
                outp[(size_t)row * 1024 + col] = fmaxf(v, 0.f);
            }
}

// ---------------- launch ----------------
extern "C" void kernel_launch(void* const* d_in, const int* in_sizes, int n_in,
                              void* d_out, int out_size, void* d_ws, size_t ws_size,
                              hipStream_t stream) {
    const float* D  = (const float*)d_in[0];
    const float* Q  = (const float*)d_in[1];
    const float* P  = (const float*)d_in[2];
    const float* Wr = (const float*)d_in[3];
    const float* br = (const float*)d_in[4];
    const float* Ur = (const float*)d_in[5];
    const float* bur= (const float*)d_in[6];
    const float* Wx = (const float*)d_in[7];
    const float* bx = (const float*)d_in[8];
    const float* U  = (const float*)d_in[9];
    const float* bu = (const float*)d_in[10];
    const float* W1 = (const float*)d_in[11];
    const float* b1 = (const float*)d_in[12];
    const float* W2 = (const float*)d_in[13];
    const float* Wm = (const float*)d_in[15];
    const float* bm = (const float*)d_in[16];

    char* ws = (char*)d_ws;
    int* flags          = (int*)ws;                                 // 256 B (64 ints)
    unsigned short* hb0 = (unsigned short*)(ws + 256);              // 128 KiB
    unsigned short* hb1 = (unsigned short*)(ws + 131328);           // 128 KiB
    unsigned short* Dc  = (unsigned short*)(ws + 262400);           // 32 MiB
    unsigned short* Qc  = (unsigned short*)(ws + 33816832);
    unsigned short* Pc  = (unsigned short*)(ws + 33947904);
    unsigned short* W1t = (unsigned short*)(ws + 34078976);         // (1024,4096)
    unsigned short* Wrxt= (unsigned short*)(ws + 42467584);         // (2048,1024)
    unsigned short* Urt = (unsigned short*)(ws + 46661888);         // (1024,1024)
    unsigned short* Utb = (unsigned short*)(ws + 48759040);         // (1024,1024)
    unsigned short* Wmt = (unsigned short*)(ws + 50856192);         // (1024,3072)
    unsigned short* Cc  = (unsigned short*)(ws + 57147648);
    float* Zpart        = (float*)(ws + 57278720);                  // (16384,4)
    float* Gt           = (float*)(ws + 57540864);                  // (256,64)
    unsigned short* Drwt= (unsigned short*)(ws + 57606400);         // (256,64,2048) bf16

    float* outNM = (float*)d_out;
    float* hsOut = (float*)d_out + 65536;

    hipMemsetAsync(ws, 0, 262400, stream);  // flags + h0 = zeros

    k_cast<<<16384, 256, 0, stream>>>(D, Dc, 4194304);
    k_cast<<<64, 256, 0, stream>>>(Q, Qc, 16384);
    k_cast<<<64, 256, 0, stream>>>(P, Pc, 16384);
    k_transpose_bf16<<<dim3(32, 128), 256, 0, stream>>>(W1, W1t, 4096, 1024);
    k_transpose_bf16<<<dim3(32, 32), 256, 0, stream>>>(Wr, Wrxt, 1024, 1024);
    k_transpose_bf16<<<dim3(32, 32), 256, 0, stream>>>(Wx, Wrxt + (size_t)1024 * 1024, 1024, 1024);
    k_transpose_bf16<<<dim3(32, 32), 256, 0, stream>>>(Ur, Urt, 1024, 1024);
    k_transpose_bf16<<<dim3(32, 32), 256, 0, stream>>>(U, Utb, 1024, 1024);
    k_transpose_bf16<<<dim3(32, 96), 256, 0, stream>>>(Wm, Wmt, 3072, 1024);

    k_gemm1<<<dim3(4, 128), 256, 0, stream>>>(Dc, Qc, Pc, W1t, b1, W2, Zpart);
    k_gemm2<<<dim3(8, 128), 256, 0, stream>>>(Dc, Wrxt, br, bx, Drwt);
    k_softmax<<<64, 256, 0, stream>>>(Zpart, Gt);
    k_scan<<<64, 256, 0, stream>>>(Urt, Utb, Drwt, Gt, bur, bu, hb0, hb1, Cc, hsOut, flags);
    k_final<<<8, 256, 0, stream>>>(Pc, Cc, Qc, Wmt, bm, outNM);
}

// Round 3
// 3072.391 us; speedup vs baseline: 1.9554x; 1.0379x over previous
//
#include <hip/hip_runtime.h>
#include <stdint.h>

typedef __bf16 bf16x8 __attribute__((ext_vector_type(8)));
typedef float f32x4 __attribute__((ext_vector_type(4)));

__device__ __forceinline__ float bf2f(unsigned short h) {
    union { unsigned int u; float f; } v; v.u = ((unsigned int)h) << 16; return v.f;
}
__device__ __forceinline__ unsigned short f2bf(float f) {  // RNE
    union { float f; unsigned int u; } v; v.f = f;
    unsigned int r = (v.u + 0x7FFFu + ((v.u >> 16) & 1u)) >> 16;
    return (unsigned short)r;
}
__device__ __forceinline__ unsigned short f2bf_trunc(float f) {
    union { float f; unsigned int u; } v; v.f = f;
    return (unsigned short)(v.u >> 16);
}
__device__ __forceinline__ bf16x8 ldfrag(const unsigned short* p) {
    uint4 u = *(const uint4*)p; return __builtin_bit_cast(bf16x8, u);
}
// coherent (MALL-direct) 16B fragment load as 2x8B relaxed agent atomics
__device__ __forceinline__ bf16x8 ldfrag_coh(const unsigned short* p) {
    union { unsigned long long q[2]; bf16x8 v; } u;
    u.q[0] = __hip_atomic_load((const unsigned long long*)p, __ATOMIC_RELAXED, __HIP_MEMORY_SCOPE_AGENT);
    u.q[1] = __hip_atomic_load((const unsigned long long*)(p + 4), __ATOMIC_RELAXED, __HIP_MEMORY_SCOPE_AGENT);
    return u.v;
}
__device__ __forceinline__ float fsigm(float x) { return 1.f / (1.f + __expf(-x)); }
__device__ __forceinline__ float ftanh(float x) { float e = __expf(2.f * x); return 1.f - 2.f / (e + 1.f); }

// ---------------- casts / transposes ----------------
__global__ __launch_bounds__(256) void k_cast(const float* __restrict__ src,
                                              unsigned short* __restrict__ dst, int n4) {
    int i = blockIdx.x * 256 + threadIdx.x;
    if (i >= n4) return;
    float4 v = ((const float4*)src)[i];
    union { unsigned short s[4]; uint2 u; } o;
    o.s[0] = f2bf(v.x); o.s[1] = f2bf(v.y); o.s[2] = f2bf(v.z); o.s[3] = f2bf(v.w);
    ((uint2*)dst)[i] = o.u;
}

// src (R,C) fp32 -> dst (C,R) bf16
__global__ __launch_bounds__(256) void k_transpose_bf16(const float* __restrict__ src,
                                                        unsigned short* __restrict__ dst,
                                                        int R, int C) {
    __shared__ float tile[32][33];
    int tc = threadIdx.x & 31, tr = threadIdx.x >> 5;  // tr 0..7
    int r0 = blockIdx.y * 32, c0 = blockIdx.x * 32;
#pragma unroll
    for (int p = 0; p < 4; p++) tile[tr + p * 8][tc] = src[(size_t)(r0 + tr + p * 8) * C + c0 + tc];
    __syncthreads();
#pragma unroll
    for (int p = 0; p < 4; p++) dst[(size_t)(c0 + tr + p * 8) * R + r0 + tc] = f2bf(tile[tc][tr + p * 8]);
}

// ---------------- GEMM1: Zs partials (z on the fly, fused tanh*W2 reduce) ----------------
// grid (4, 128); tile 128(M) x 256(N); K=4096
__global__ __launch_bounds__(256, 2) void k_gemm1(
    const unsigned short* __restrict__ Dc, const unsigned short* __restrict__ Qc,
    const unsigned short* __restrict__ Pc, const unsigned short* __restrict__ W1t,
    const float* __restrict__ b1, const float* __restrict__ W2, float* __restrict__ Zpart) {
    __shared__ alignas(16) unsigned short As[128][40];
    __shared__ alignas(16) unsigned short Bs[256][40];
    __shared__ float red[128];
    const int tid = threadIdx.x;
    const int nt = blockIdx.x, mt = blockIdx.y;
    const int r0 = mt * 128, n0 = nt * 256, b = r0 >> 8;
    const int lane = tid & 63, wid = tid >> 6;
    const int qm = wid & 1, qn = wid >> 1;
    const int nlane = lane & 15, quad = lane >> 4, k0 = quad * 8;

    f32x4 acc[4][8];
#pragma unroll
    for (int im = 0; im < 4; im++)
#pragma unroll
        for (int in = 0; in < 8; in++) acc[im][in] = (f32x4){0.f, 0.f, 0.f, 0.f};

    for (int kt = 0; kt < 128; ++kt) {
        const int q = kt >> 5;               // quarter of z
        const int kq = (kt & 31) * 32;       // k within quarter
        const unsigned short* wsrc = (q & 1) ? Pc : Qc;
#pragma unroll
        for (int rep = 0; rep < 2; ++rep) {
            int c = tid + rep * 256;
            int row = c >> 2, part = c & 3;
            uint4 d8 = *(const uint4*)(Dc + (size_t)(r0 + row) * 1024 + kq + part * 8);
            uint4 w8 = *(const uint4*)(wsrc + (size_t)b * 1024 + kq + part * 8);
            const unsigned short* d16 = (const unsigned short*)&d8;
            const unsigned short* w16 = (const unsigned short*)&w8;
            uint4 o; unsigned short* o16 = (unsigned short*)&o;
#pragma unroll
            for (int j = 0; j < 8; j++) {
                float dv = bf2f(d16[j]), wv = bf2f(w16[j]);
                float r = (q < 2) ? dv * wv : fabsf(dv - wv);
                o16[j] = f2bf_trunc(r);
            }
            *(uint4*)&As[row][part * 8] = o;
        }
#pragma unroll
        for (int rep = 0; rep < 4; ++rep) {
            int c = tid + rep * 256;
            int n = c >> 2, part = c & 3;
            *(uint4*)&Bs[n][part * 8] =
                *(const uint4*)(W1t + (size_t)(n0 + n) * 4096 + kt * 32 + part * 8);
        }
        __syncthreads();
        bf16x8 af[4], bfr[8];
#pragma unroll
        for (int im = 0; im < 4; im++) af[im] = ldfrag(&As[qm * 64 + im * 16 + nlane][k0]);
#pragma unroll
        for (int in = 0; in < 8; in++) bfr[in] = ldfrag(&Bs[qn * 128 + in * 16 + nlane][k0]);
#pragma unroll
        for (int im = 0; im < 4; im++)
#pragma unroll
            for (int in = 0; in < 8; in++)
                acc[im][in] = __builtin_amdgcn_mfma_f32_16x16x32_bf16(af[im], bfr[in], acc[im][in], 0, 0, 0);
        __syncthreads();
    }
    if (tid < 128) red[tid] = 0.f;
    __syncthreads();
    float b1v[8], w2v[8];
#pragma unroll
    for (int in = 0; in < 8; in++) {
        int col = n0 + qn * 128 + in * 16 + nlane;
        b1v[in] = b1[col]; w2v[in] = W2[col];
    }
#pragma unroll
    for (int im = 0; im < 4; im++)
#pragma unroll
        for (int i = 0; i < 4; i++) {
            float s = 0.f;
#pragma unroll
            for (int in = 0; in < 8; in++) s += ftanh(acc[im][in][i] + b1v[in]) * w2v[in];
            s += __shfl_xor(s, 1); s += __shfl_xor(s, 2); s += __shfl_xor(s, 4); s += __shfl_xor(s, 8);
            if (nlane == 0) atomicAdd(&red[qm * 64 + im * 16 + quad * 4 + i], s);
        }
    __syncthreads();
    if (tid < 128) Zpart[(size_t)(r0 + tid) * 4 + nt] = red[tid];
}

// ---------------- GEMM2: [Dr|Dw] = D @ [Wr|Wx] + [br|bx], store bf16 transposed (t,b,:) ----------------
// grid (8, 128); tile 128 x 256; K=1024
__global__ __launch_bounds__(256, 2) void k_gemm2(
    const unsigned short* __restrict__ Dc, const unsigned short* __restrict__ Wrxt,
    const float* __restrict__ br, const float* __restrict__ bx,
    unsigned short* __restrict__ Drwt) {
    __shared__ alignas(16) unsigned short As[128][40];
    __shared__ alignas(16) unsigned short Bs[256][40];
    const int tid = threadIdx.x;
    const int nt = blockIdx.x, mt = blockIdx.y;
    const int r0 = mt * 128, n0 = nt * 256;
    const int lane = tid & 63, wid = tid >> 6;
    const int qm = wid & 1, qn = wid >> 1;
    const int nlane = lane & 15, quad = lane >> 4, k0 = quad * 8;

    f32x4 acc[4][8];
#pragma unroll
    for (int im = 0; im < 4; im++)
#pragma unroll
        for (int in = 0; in < 8; in++) acc[im][in] = (f32x4){0.f, 0.f, 0.f, 0.f};

    for (int kt = 0; kt < 32; ++kt) {
#pragma unroll
        for (int rep = 0; rep < 2; ++rep) {
            int c = tid + rep * 256;
            int row = c >> 2, part = c & 3;
            *(uint4*)&As[row][part * 8] =
                *(const uint4*)(Dc + (size_t)(r0 + row) * 1024 + kt * 32 + part * 8);
        }
#pragma unroll
        for (int rep = 0; rep < 4; ++rep) {
            int c = tid + rep * 256;
            int n = c >> 2, part = c & 3;
            *(uint4*)&Bs[n][part * 8] =
                *(const uint4*)(Wrxt + (size_t)(n0 + n) * 1024 + kt * 32 + part * 8);
        }
        __syncthreads();
        bf16x8 af[4], bfr[8];
#pragma unroll
        for (int im = 0; im < 4; im++) af[im] = ldfrag(&As[qm * 64 + im * 16 + nlane][k0]);
#pragma unroll
        for (int in = 0; in < 8; in++) bfr[in] = ldfrag(&Bs[qn * 128 + in * 16 + nlane][k0]);
#pragma unroll
        for (int im = 0; im < 4; im++)
#pragma unroll
            for (int in = 0; in < 8; in++)
                acc[im][in] = __builtin_amdgcn_mfma_f32_16x16x32_bf16(af[im], bfr[in], acc[im][in], 0, 0, 0);
        __syncthreads();
    }
    float bias[8];
#pragma unroll
    for (int in = 0; in < 8; in++) {
        int col = n0 + qn * 128 + in * 16 + nlane;
        bias[in] = (col < 1024) ? br[col] : bx[col - 1024];
    }
#pragma unroll
    for (int im = 0; im < 4; im++)
#pragma unroll
        for (int i = 0; i < 4; i++) {
            int r = r0 + qm * 64 + im * 16 + quad * 4 + i;
            int bb = r >> 8, t = r & 255;
            unsigned short* dp = Drwt + ((size_t)t * 64 + bb) * 2048;
#pragma unroll
            for (int in = 0; in < 8; in++) {
                int col = n0 + qn * 128 + in * 16 + nlane;
                dp[col] = f2bf(acc[im][in][i] + bias[in]);
            }
        }
}

// ---------------- softmax over S per batch ----------------
__global__ __launch_bounds__(256) void k_softmax(const float* __restrict__ Zpart,
                                                 float* __restrict__ Gt) {
    int b = blockIdx.x, s = threadIdx.x;
    const float* zp = Zpart + ((size_t)b * 256 + s) * 4;
    float l = zp[0] + zp[1] + zp[2] + zp[3];
    __shared__ float sm[4], ss[4];
    int lane = s & 63, wid = s >> 6;
    float m = l;
#pragma unroll
    for (int o = 32; o; o >>= 1) m = fmaxf(m, __shfl_xor(m, o));
    if (lane == 0) sm[wid] = m;
    __syncthreads();
    m = fmaxf(fmaxf(sm[0], sm[1]), fmaxf(sm[2], sm[3]));
    float e = __expf(l - m);
    float sum = e;
#pragma unroll
    for (int o = 32; o; o >>= 1) sum += __shfl_xor(sum, o);
    if (lane == 0) ss[wid] = sum;
    __syncthreads();
    sum = ss[0] + ss[1] + ss[2] + ss[3];
    Gt[(size_t)s * 64 + b] = e / sum;
}

// ---------------- scan v3 ----------------
// BIG=1: 256 per-step h buffers; producer sc1 write-through stores, consumer PLAIN
//        cached loads (fresh-by-construction addresses; L2-shared across the XCD).
// BIG=0: 2 alternating buffers, consumer sc1 (MALL) loads.
// Both: all 32 h-fragment loads issued as one batch; all-wave flag poll with a
// data-dependence (dep) pinning h loads after the barrier.
template <int BIG>
__global__ __launch_bounds__(256, 1) void k_scan(
    const unsigned short* __restrict__ Urt, const unsigned short* __restrict__ Ut,
    const unsigned short* __restrict__ Drwt, const float* __restrict__ Gt,
    const float* __restrict__ bur, const float* __restrict__ bu,
    unsigned short* __restrict__ hb,
    unsigned short* __restrict__ Cc, float* __restrict__ hs, int* __restrict__ flags) {
    const int w = blockIdx.x;                 // column slice
    const int tid = threadIdx.x, lane = tid & 63, wv = tid >> 6;
    const int nlane = lane & 15, quad = lane >> 4;
    const int n = w * 16 + nlane;             // output column
    const int m0 = wv * 16;                   // batch-row base of this wave
    const int brow = m0 + quad * 4;           // +i = batch row of acc elem i

    // weight slices resident in AGPRs for all 256 steps
    bf16x8 BU[32], BW[32];
#pragma unroll
    for (int ks = 0; ks < 32; ks++) {
        int kk = ks * 32 + quad * 8;
        BU[ks] = ldfrag(Urt + (size_t)n * 1024 + kk);
        BW[ks] = ldfrag(Ut + (size_t)n * 1024 + kk);
    }
    const float burj = bur[n], buj = bu[n];
    float hst[4] = {0.f, 0.f, 0.f, 0.f};
    size_t dep = 0;  // always 0, but data-dependent on the poll result

    float dr[4], dw[4], g[4];
#pragma unroll
    for (int i = 0; i < 4; i++) {
        int r = brow + i;
        const unsigned short* dp = Drwt + (size_t)r * 2048;
        dr[i] = bf2f(dp[n]); dw[i] = bf2f(dp[1024 + n]); g[i] = Gt[r];
    }

#pragma unroll 1
    for (int t = 0; t < 256; t++) {
        const unsigned short* hcur = hb + (((size_t)(BIG ? t : (t & 1))) << 16) + dep;
        unsigned short* hnxt = hb + (((size_t)(BIG ? (t + 1) : ((t + 1) & 1))) << 16);
        const unsigned short* hrow = hcur + (size_t)(m0 + nlane) * 1024 + quad * 8;

        // batch ALL fragment loads (concurrent in flight)
        bf16x8 hf[32];
#pragma unroll
        for (int ks = 0; ks < 32; ks++)
            hf[ks] = BIG ? ldfrag(hrow + ks * 32) : ldfrag_coh(hrow + ks * 32);

        f32x4 aU0 = {0.f,0.f,0.f,0.f}, aU1 = {0.f,0.f,0.f,0.f};
        f32x4 aW0 = {0.f,0.f,0.f,0.f}, aW1 = {0.f,0.f,0.f,0.f};
#pragma unroll
        for (int ks = 0; ks < 32; ks += 2) {
            aU0 = __builtin_amdgcn_mfma_f32_16x16x32_bf16(hf[ks], BU[ks], aU0, 0, 0, 0);
            aW0 = __builtin_amdgcn_mfma_f32_16x16x32_bf16(hf[ks], BW[ks], aW0, 0, 0, 0);
            aU1 = __builtin_amdgcn_mfma_f32_16x16x32_bf16(hf[ks + 1], BU[ks + 1], aU1, 0, 0, 0);
            aW1 = __builtin_amdgcn_mfma_f32_16x16x32_bf16(hf[ks + 1], BW[ks + 1], aW1, 0, 0, 0);
        }

#pragma unroll
        for (int i = 0; i < 4; i++) {
            float r = fsigm(dr[i] + aU0[i] + aU1[i] + burj);
            float ht = ftanh(dw[i] + r * (aW0[i] + aW1[i] + buj));
            float hn = g[i] * ht + (1.f - g[i]) * hst[i];
            hst[i] = hn;
            int row = brow + i;
            if (t < 255)
                __hip_atomic_store(&hnxt[(size_t)row * 1024 + n], f2bf(hn),
                                   __ATOMIC_RELAXED, __HIP_MEMORY_SCOPE_AGENT);
            hs[((size_t)row * 256 + t) * 1024 + n] = hn;
        }
        if (t == 255) {
#pragma unroll
            for (int i = 0; i < 4; i++) Cc[(size_t)(brow + i) * 1024 + n] = f2bf(hst[i]);
        } else {
            // prefetch next step's inputs (latency hides under the barrier drain)
            float drn[4], dwn[4], gn[4];
#pragma unroll
            for (int i = 0; i < 4; i++) {
                int r = brow + i;
                const unsigned short* dp = Drwt + ((size_t)(t + 1) * 64 + r) * 2048;
                drn[i] = bf2f(dp[n]); dwn[i] = bf2f(dp[1024 + n]); gn[i] = Gt[(t + 1) * 64 + r];
            }
            __syncthreads();  // drains all waves' h stores (vmcnt 0)
            if (tid == 0)
                __hip_atomic_store(&flags[w], t + 1, __ATOMIC_RELAXED, __HIP_MEMORY_SCOPE_AGENT);
            const int tgt = t + 1;
            int myv;
            do {
                myv = __hip_atomic_load(&flags[lane], __ATOMIC_RELAXED, __HIP_MEMORY_SCOPE_AGENT);
            } while (__ballot(myv >= tgt) != ~0ull);
            dep += (myv >= tgt) ? 0 : 1;  // 0; forces h loads after poll
#pragma unroll
            for (int i = 0; i < 4; i++) { dr[i] = drn[i]; dw[i] = dwn[i]; g[i] = gn[i]; }
        }
    }
}

// ---------------- final: next_mem = relu([prev|C|Q] @ Wm + bm) ----------------
// grid 8; tile 64 x 128; K=3072
__global__ __launch_bounds__(256) void k_final(
    const unsigned short* __restrict__ Pc, const unsigned short* __restrict__ Cc,
    const unsigned short* __restrict__ Qc, const unsigned short* __restrict__ Wmt,
    const float* __restrict__ bm, float* __restrict__ outp) {
    __shared__ alignas(16) unsigned short As[64][40];
    __shared__ alignas(16) unsigned short Bs[128][40];
    const int tid = threadIdx.x;
    const int n0 = blockIdx.x * 128;
    const int lane = tid & 63, wid = tid >> 6;
    const int nlane = lane & 15, quad = lane >> 4, k0 = quad * 8;
    f32x4 acc[4][2];
#pragma unroll
    for (int im = 0; im < 4; im++) { acc[im][0] = (f32x4){0.f,0.f,0.f,0.f}; acc[im][1] = (f32x4){0.f,0.f,0.f,0.f}; }

    for (int kt = 0; kt < 96; ++kt) {
        {
            int row = tid >> 2, part = tid & 3;
            int kk = kt * 32 + part * 8;
            int sec = kk >> 10, off = kk & 1023;
            const unsigned short* sp = (sec == 0) ? Pc : (sec == 1) ? Cc : Qc;
            *(uint4*)&As[row][part * 8] = *(const uint4*)(sp + (size_t)row * 1024 + off);
        }
#pragma unroll
        for (int rep = 0; rep < 2; rep++) {
            int c = tid + rep * 256;
            int n = c >> 2, part = c & 3;
            *(uint4*)&Bs[n][part * 8] =
                *(const uint4*)(Wmt + (size_t)(n0 + n) * 3072 + kt * 32 + part * 8);
        }
        __syncthreads();
        bf16x8 af[4], bfr[2];
#pragma unroll
        for (int im = 0; im < 4; im++) af[im] = ldfrag(&As[im * 16 + nlane][k0]);
#pragma unroll
        for (int in = 0; in < 2; in++) bfr[in] = ldfrag(&Bs[wid * 32 + in * 16 + nlane][k0]);
#pragma unroll
        for (int im = 0; im < 4; im++)
#pragma unroll
            for (int in = 0; in < 2; in++)
                acc[im][in] = __builtin_amdgcn_mfma_f32_16x16x32_bf16(af[im], bfr[in], acc[im][in], 0, 0, 0);
        __syncthreads();
    }
#pragma unroll
    for (int im = 0; im < 4; im++)
#pragma unroll
        for (int i = 0; i < 4; i++)
#pragma unroll
            for (int in = 0; in < 2; in++) {
                int row = im * 16 + quad * 4 + i;
                int col = n0 + wid * 32 + in * 16 + nlane;
                float v = acc[im][in][i] + bm[col];
                outp[(size_t)row * 1024 + col] = fmaxf(v, 0.f);
            }
}

// ---------------- launch ----------------
extern "C" void kernel_launch(void* const* d_in, const int* in_sizes, int n_in,
                              void* d_out, int out_size, void* d_ws, size_t ws_size,
                              hipStream_t stream) {
    const float* D  = (const float*)d_in[0];
    const float* Q  = (const float*)d_in[1];
    const float* P  = (const float*)d_in[2];
    const float* Wr = (const float*)d_in[3];
    const float* br = (const float*)d_in[4];
    const float* Ur = (const float*)d_in[5];
    const float* bur= (const float*)d_in[6];
    const float* Wx = (const float*)d_in[7];
    const float* bx = (const float*)d_in[8];
    const float* U  = (const float*)d_in[9];
    const float* bu = (const float*)d_in[10];
    const float* W1 = (const float*)d_in[11];
    const float* b1 = (const float*)d_in[12];
    const float* W2 = (const float*)d_in[13];
    const float* Wm = (const float*)d_in[15];
    const float* bm = (const float*)d_in[16];

    char* ws = (char*)d_ws;
    const size_t HB_BIG = 33554432ull;   // 256 step-buffers x 128 KiB
    const size_t HB_SMALL = 262144ull;   // 2 buffers
    // common block sizes (bytes)
    const size_t SZ_Dc = 33554432, SZ_Qc = 131072, SZ_Pc = 131072, SZ_W1t = 8388608,
                 SZ_Wrxt = 4194304, SZ_Urt = 2097152, SZ_Utb = 2097152, SZ_Wmt = 6291456,
                 SZ_Cc = 131072, SZ_Zp = 262144, SZ_Gt = 65536, SZ_Drwt = 67108864;
    const size_t common = SZ_Dc + SZ_Qc + SZ_Pc + SZ_W1t + SZ_Wrxt + SZ_Urt + SZ_Utb +
                          SZ_Wmt + SZ_Cc + SZ_Zp + SZ_Gt + SZ_Drwt;  // 124,452,864
    const bool big = ws_size >= 4096 + HB_BIG + common;              // 158,011,392

    size_t cur = 0;
    int* flags          = (int*)(ws + cur);            cur += 4096;
    unsigned short* hb  = (unsigned short*)(ws + cur); cur += big ? HB_BIG : HB_SMALL;
    unsigned short* Dc  = (unsigned short*)(ws + cur); cur += SZ_Dc;
    unsigned short* Qc  = (unsigned short*)(ws + cur); cur += SZ_Qc;
    unsigned short* Pc  = (unsigned short*)(ws + cur); cur += SZ_Pc;
    unsigned short* W1t = (unsigned short*)(ws + cur); cur += SZ_W1t;
    unsigned short* Wrxt= (unsigned short*)(ws + cur); cur += SZ_Wrxt;
    unsigned short* Urt = (unsigned short*)(ws + cur); cur += SZ_Urt;
    unsigned short* Utb = (unsigned short*)(ws + cur); cur += SZ_Utb;
    unsigned short* Wmt = (unsigned short*)(ws + cur); cur += SZ_Wmt;
    unsigned short* Cc  = (unsigned short*)(ws + cur); cur += SZ_Cc;
    float* Zpart        = (float*)(ws + cur);          cur += SZ_Zp;
    float* Gt           = (float*)(ws + cur);          cur += SZ_Gt;
    unsigned short* Drwt= (unsigned short*)(ws + cur); cur += SZ_Drwt;

    float* outNM = (float*)d_out;
    float* hsOut = (float*)d_out + 65536;

    hipMemsetAsync(ws, 0, 4096 + 131072, stream);  // flags + h buffer 0

    k_cast<<<16384, 256, 0, stream>>>(D, Dc, 4194304);
    k_cast<<<64, 256, 0, stream>>>(Q, Qc, 16384);
    k_cast<<<64, 256, 0, stream>>>(P, Pc, 16384);
    k_transpose_bf16<<<dim3(32, 128), 256, 0, stream>>>(W1, W1t, 4096, 1024);
    k_transpose_bf16<<<dim3(32, 32), 256, 0, stream>>>(Wr, Wrxt, 1024, 1024);
    k_transpose_bf16<<<dim3(32, 32), 256, 0, stream>>>(Wx, Wrxt + (size_t)1024 * 1024, 1024, 1024);
    k_transpose_bf16<<<dim3(32, 32), 256, 0, stream>>>(Ur, Urt, 1024, 1024);
    k_transpose_bf16<<<dim3(32, 32), 256, 0, stream>>>(U, Utb, 1024, 1024);
    k_transpose_bf16<<<dim3(32, 96), 256, 0, stream>>>(Wm, Wmt, 3072, 1024);

    k_gemm1<<<dim3(4, 128), 256, 0, stream>>>(Dc, Qc, Pc, W1t, b1, W2, Zpart);
    k_gemm2<<<dim3(8, 128), 256, 0, stream>>>(Dc, Wrxt, br, bx, Drwt);
    k_softmax<<<64, 256, 0, stream>>>(Zpart, Gt);
    if (big)
        k_scan<1><<<64, 256, 0, stream>>>(Urt, Utb, Drwt, Gt, bur, bu, hb, Cc, hsOut, flags);
    else
        k_scan<0><<<64, 256, 0, stream>>>(Urt, Utb, Drwt, Gt, bur, bu, hb, Cc, hsOut, flags);
    k_final<<<8, 256, 0, stream>>>(Pc, Cc, Qc, Wmt, bm, outNM);
}